// Round 4
// baseline (184.915 us; speedup 1.0000x reference)
//
#include <hip/hip_runtime.h>
#include <hip/hip_bf16.h>
#include <math.h>

typedef unsigned short ushort_t;
typedef __attribute__((ext_vector_type(8))) short bf16x8;
typedef __attribute__((ext_vector_type(4))) float f32x4;
typedef __attribute__((ext_vector_type(2))) float f32x2;

constexpr int BATCH   = 4;
constexpr int D_MODEL = 256;
constexpr int LEN_IN  = 5440;
constexpr int LEN_Q   = 5440;
constexpr int M_TOT   = BATCH * LEN_Q;   // 21760

#define ASG __attribute__((address_space(1)))
#define ASL __attribute__((address_space(3)))

__device__ __forceinline__ void gld16(const void* g, void* l) {
    __builtin_amdgcn_global_load_lds((ASG const void*)g, (ASL void*)l, 16, 0, 0);
}

__device__ __forceinline__ ushort_t bfbits(float x) {
    __hip_bfloat16 h = __float2bfloat16(x);
    ushort_t u; __builtin_memcpy(&u, &h, 2); return u;
}
__device__ __forceinline__ unsigned pk2(float a, float b) {
    return (unsigned)bfbits(a) | ((unsigned)bfbits(b) << 16);
}

// ======================= weight prep (tiny) =======================
__global__ __launch_bounds__(256) void pack_weights(
    const float* __restrict__ Wv, const float* __restrict__ Wout,
    const float* __restrict__ Wo, const float* __restrict__ Wa,
    const float* __restrict__ b_off, const float* __restrict__ b_attn,
    ushort_t* __restrict__ wvT, ushort_t* __restrict__ woutT,
    ushort_t* __restrict__ woaT, float* __restrict__ bias_oa)
{
    const int blk = blockIdx.x, t = threadIdx.x;
    if (blk < 64) {
        const float* src = (blk < 32) ? Wv : Wout;
        ushort_t*    dst = (blk < 32) ? wvT : woutT;
        const int k0 = (blk & 31) * 8;
        float f[8];
#pragma unroll
        for (int i = 0; i < 8; i++) f[i] = src[(k0 + i) * 256 + t];
        *(uint4*)(dst + t * 256 + k0) =
            make_uint4(pk2(f[0], f[1]), pk2(f[2], f[3]),
                       pk2(f[4], f[5]), pk2(f[6], f[7]));
    } else if (blk < 96) {
        const int k0 = (blk - 64) * 8;
#pragma unroll
        for (int rep = 0; rep < 2; rep++) {
            const int j = (rep == 0) ? t : 256 + t;
            if (rep == 1 && t >= 128) break;
            float f[8];
#pragma unroll
            for (int i = 0; i < 8; i++)
                f[i] = (j < 256) ? Wo[(k0 + i) * 256 + j]
                                 : Wa[(k0 + i) * 128 + (j - 256)];
            *(uint4*)(woaT + j * 256 + k0) =
                make_uint4(pk2(f[0], f[1]), pk2(f[2], f[3]),
                           pk2(f[4], f[5]), pk2(f[6], f[7]));
        }
    } else {
        bias_oa[t] = b_off[t];
        if (t < 128) bias_oa[256 + t] = b_attn[t];
    }
}

// ======================= bf16 MFMA GEMM core (N-blocked) =======================
// OUT_MODE: 0 = f32 row-major, 2 = bf16 head-major value
// A_F32: A is raw f32; reg-stage (float4 x2 -> cvt -> ds_write_b128) into the
//        same LDS layout gld16 produces.
// NB: number of 128-wide bn tiles per block; A staged ONCE per K-step and
//     reused for NB*16 MFMAs (halves A traffic + staging VALU for NB=2).
template <int OUT_MODE, bool A_F32, int NB>
__device__ __forceinline__ void gemm_core(
    const void* __restrict__ Ap, const ushort_t* __restrict__ BT,
    const float* __restrict__ bias, void* __restrict__ Cp, int N,
    int bm, int bn, ushort_t* As, ushort_t* Bs)
{
    const int tid  = threadIdx.x;
    const int wave = tid >> 6, lane = tid & 63;
    const int wm = (wave >> 1) * 64, wn = (wave & 1) * 64;
    const int c0 = 2 * wave, c1 = 2 * wave + 1;
    const int kb = (lane & 3) * 8;
    const int ar0 = bm + c0 * 16 + (lane >> 2);
    const int ar1 = bm + c1 * 16 + (lane >> 2);
    const ushort_t* gA0h = nullptr; const ushort_t* gA1h = nullptr;
    const float*    gA0f = nullptr; const float*    gA1f = nullptr;
    if (A_F32) {
        gA0f = (const float*)Ap + (size_t)ar0 * 256 + kb;
        gA1f = (const float*)Ap + (size_t)ar1 * 256 + kb;
    } else {
        gA0h = (const ushort_t*)Ap + (size_t)ar0 * 256 + kb;
        gA1h = (const ushort_t*)Ap + (size_t)ar1 * 256 + kb;
    }
    const ushort_t* gB0[NB]; const ushort_t* gB1[NB];
    ushort_t* lB0[NB]; ushort_t* lB1[NB];
#pragma unroll
    for (int nb = 0; nb < NB; nb++) {
        gB0[nb] = BT + (size_t)(bn + nb * 128 + c0 * 16 + (lane >> 2)) * 256 + kb;
        gB1[nb] = BT + (size_t)(bn + nb * 128 + c1 * 16 + (lane >> 2)) * 256 + kb;
        lB0[nb] = Bs + nb * 4096 + c0 * 512;
        lB1[nb] = Bs + nb * 4096 + c1 * 512;
    }
    ushort_t* lA0 = As + c0 * 512;   // wave-uniform chunk base
    ushort_t* lA1 = As + c1 * 512;

    f32x4 acc[NB][4][4] = {};
    const int row = lane & 15, kg = (lane >> 4) * 8;
    for (int kt = 0; kt < 8; kt++) {
        if (A_F32) {
            float4 a0 = *(const float4*)gA0f;
            float4 a1 = *(const float4*)(gA0f + 4);
            float4 b0 = *(const float4*)gA1f;
            float4 b1 = *(const float4*)(gA1f + 4);
            *(uint4*)(lA0 + lane * 8) =
                make_uint4(pk2(a0.x, a0.y), pk2(a0.z, a0.w),
                           pk2(a1.x, a1.y), pk2(a1.z, a1.w));
            *(uint4*)(lA1 + lane * 8) =
                make_uint4(pk2(b0.x, b0.y), pk2(b0.z, b0.w),
                           pk2(b1.x, b1.y), pk2(b1.z, b1.w));
            gA0f += 32; gA1f += 32;
        } else {
            gld16(gA0h, lA0); gld16(gA1h, lA1);
            gA0h += 32; gA1h += 32;
        }
#pragma unroll
        for (int nb = 0; nb < NB; nb++) {
            gld16(gB0[nb], lB0[nb]); gld16(gB1[nb], lB1[nb]);
            gB0[nb] += 32; gB1[nb] += 32;
        }
        __syncthreads();
        bf16x8 af[4];
#pragma unroll
        for (int i = 0; i < 4; i++)
            af[i] = *(const bf16x8*)(As + (wm + i * 16 + row) * 32 + kg);
#pragma unroll
        for (int nb = 0; nb < NB; nb++) {
            bf16x8 bfr[4];
#pragma unroll
            for (int j = 0; j < 4; j++)
                bfr[j] = *(const bf16x8*)(Bs + nb * 4096 + (wn + j * 16 + row) * 32 + kg);
#pragma unroll
            for (int i = 0; i < 4; i++)
#pragma unroll
                for (int j = 0; j < 4; j++)
                    acc[nb][i][j] = __builtin_amdgcn_mfma_f32_16x16x32_bf16(
                        af[i], bfr[j], acc[nb][i][j], 0, 0, 0);
        }
        __syncthreads();
    }

    const int col = lane & 15, rbase = (lane >> 4) * 4;
#pragma unroll
    for (int nb = 0; nb < NB; nb++) {
#pragma unroll
        for (int j = 0; j < 4; j++) {
            const int cc = bn + nb * 128 + wn + j * 16 + col;
            const float bv = bias[cc];
#pragma unroll
            for (int i = 0; i < 4; i++) {
                const int rr = bm + wm + i * 16 + rbase;
#pragma unroll
                for (int r = 0; r < 4; r++) {
                    const float v = acc[nb][i][j][r] + bv;
                    const int m = rr + r;
                    if (OUT_MODE == 0) {
                        ((float*)Cp)[(size_t)m * N + cc] = v;
                    } else {
                        // value head-major: [b][head][pix][32]
                        const int bb  = m / LEN_IN;
                        const int pix = m - bb * LEN_IN;
                        const int head = cc >> 5, ch = cc & 31;
                        ((ushort_t*)Cp)[((size_t)((bb * 8 + head) * LEN_IN + pix) << 5) + ch] = bfbits(v);
                    }
                }
            }
        }
    }
}

// 510 blocks: [0,170) value NB=2; [170,340) offattn bn{0,128}; [340,510) offattn bn{256}
__global__ __launch_bounds__(256) void gemm_dual(
    const float* __restrict__ inflat, const ushort_t* __restrict__ wvT,
    const float* __restrict__ b_val, ushort_t* __restrict__ value_bf,
    const float* __restrict__ query, const ushort_t* __restrict__ woaT,
    const float* __restrict__ bias_oa, float* __restrict__ offattn)
{
    __shared__ ushort_t As[128 * 32];
    __shared__ ushort_t Bs[2 * 128 * 32];
    const int blk = blockIdx.x;
    if (blk < 170) {
        gemm_core<2, true, 2>(inflat, wvT, b_val, value_bf, 256,
                              blk * 128, 0, As, Bs);
    } else if (blk < 340) {
        gemm_core<0, true, 2>(query, woaT, bias_oa, offattn, 384,
                              (blk - 170) * 128, 0, As, Bs);
    } else {
        gemm_core<0, true, 1>(query, woaT, bias_oa, offattn, 384,
                              (blk - 340) * 128, 256, As, Bs);
    }
}

__global__ __launch_bounds__(256) void gemm_out(
    const ushort_t* __restrict__ mid_bf, const ushort_t* __restrict__ woutT,
    const float* __restrict__ b_out, float* __restrict__ out)
{
    __shared__ ushort_t As[128 * 32];
    __shared__ ushort_t Bs[128 * 32];
    const int bn = (blockIdx.x & 1) * 128, bm = (blockIdx.x >> 1) * 128;
    gemm_core<0, false, 1>(mid_bf, woutT, b_out, out, 256, bm, bn, As, Bs);
}

// ======================= softmax + bilinear sampling v3b =======================
// value head-major [b][h][pix][32] bf16, XCD-pinned (b,h) slices (348 KB fits
// the 4 MiB per-XCD L2). Block = 64 queries x 1 (b,h); each query served by
// 4 channel-split lanes (8 ch = 16 B each). Offsets loaded per-level to keep
// VGPR low (40) -> high occupancy for the gather latency.
__device__ __forceinline__ void accd(f32x2& a, unsigned u, f32x2 w) {
    f32x2 v;
    v.x = __uint_as_float(u << 16);
    v.y = __uint_as_float(u & 0xFFFF0000u);
    a = w * v + a;   // ffp-contract -> v_pk_fma_f32
}
__device__ __forceinline__ void accp(f32x2* a, uint4 u, float wf) {
    const f32x2 w = {wf, wf};
    accd(a[0], u.x, w); accd(a[1], u.y, w);
    accd(a[2], u.z, w); accd(a[3], u.w, w);
}

__global__ __launch_bounds__(256) void msda_sample_v3(
    const ushort_t* __restrict__ value,   // [B*8][5440][32] bf16
    const float* __restrict__ refp,
    const float* __restrict__ offattn,
    ushort_t* __restrict__ mid)
{
    const int tid = threadIdx.x;
    const unsigned bid = blockIdx.x;
    // XCD-pinned slice mapping: 85 q-chunks per (b,h), 4 (b,h) per XCD
    const int xcd   = bid & 7;
    const int pos   = bid >> 3;           // 0..339
    const int slice = pos / 85;           // 0..3
    const int qc    = pos - slice * 85;   // 0..84
    const int bh    = xcd * 4 + slice;    // 0..31
    const int b     = bh >> 3, h = bh & 7;

    const int ql = tid >> 2;              // 0..63
    const int cg = tid & 3;               // channel group (8 ch = 16 B)
    const int bq = b * LEN_Q + qc * 64 + ql;

    const float* oab = offattn + (size_t)bq * 384;
    // logits for this head
    const float* lp = oab + 256 + h * 16;
    float4 l0 = ((const float4*)lp)[0];
    float4 l1 = ((const float4*)lp)[1];
    float4 l2 = ((const float4*)lp)[2];
    float4 l3 = ((const float4*)lp)[3];
    float lg[16] = {l0.x, l0.y, l0.z, l0.w, l1.x, l1.y, l1.z, l1.w,
                    l2.x, l2.y, l2.z, l2.w, l3.x, l3.y, l3.z, l3.w};
    float mx = lg[0];
#pragma unroll
    for (int j = 1; j < 16; j++) mx = fmaxf(mx, lg[j]);

    const float* op = oab + h * 32;
    const float* rp = refp + (size_t)bq * 8;

    // lane's 16 B channel slice inside each 64 B corner block
    const char* vb = (const char*)value + (size_t)bh * (LEN_IN * 64) + cg * 16;

    f32x2 acc2[4];
#pragma unroll
    for (int d = 0; d < 4; d++) acc2[d] = (f32x2){0.f, 0.f};
    float esum = 0.f;

#pragma unroll
    for (int l = 0; l < 4; l++) {
        const int   shift = 6 - l;        // log2(W), W = 64,32,16,8 (square)
        const int   W     = 1 << shift;
        const float fW    = (float)W;
        const float invW  = __uint_as_float((unsigned)(127 - shift) << 23); // exact 2^-shift
        const int   st    = (l == 0) ? 0 : (l == 1) ? 4096 : (l == 2) ? 5120 : 5376;

        const float2 rl = *(const float2*)(rp + l * 2);
        const float4 oA = ((const float4*)op)[l * 2];
        const float4 oB = ((const float4*)op)[l * 2 + 1];
        const float oxA[4] = {oA.x, oA.z, oB.x, oB.z};
        const float oyA[4] = {oA.y, oA.w, oB.y, oB.w};
#pragma unroll
        for (int p = 0; p < 4; p++) {
            const float x = (rl.x + oxA[p] * invW) * fW - 0.5f;
            const float y = (rl.y + oyA[p] * invW) * fW - 0.5f;
            const float x0f = floorf(x), y0f = floorf(y);
            const float wx = x - x0f, wy = y - y0f;
            const int ix0 = (int)x0f, iy0 = (int)y0f;
            const int ix1 = ix0 + 1,  iy1 = iy0 + 1;
            const float vx0 = (ix0 >= 0 && ix0 < W) ? 1.f : 0.f;
            const float vx1 = (ix1 >= 0 && ix1 < W) ? 1.f : 0.f;
            const float vy0 = (iy0 >= 0 && iy0 < W) ? 1.f : 0.f;
            const float vy1 = (iy1 >= 0 && iy1 < W) ? 1.f : 0.f;
            const int cx0 = min(max(ix0, 0), W - 1);
            const int cx1 = min(max(ix1, 0), W - 1);
            const int cy0 = min(max(iy0, 0), W - 1);
            const int cy1 = min(max(iy1, 0), W - 1);
            const float hx0 = (1.f - wx) * vx0, hx1 = wx * vx1;
            const float hy0 = (1.f - wy) * vy0, hy1 = wy * vy1;

            const float e = __expf(lg[l * 4 + p] - mx);
            esum += e;
            const float w00 = e * hx0 * hy0, w01 = e * hx1 * hy0;
            const float w10 = e * hx0 * hy1, w11 = e * hx1 * hy1;

            const int r0a = st + (cy0 << shift);
            const int r1a = st + (cy1 << shift);
            uint4 v00 = *(const uint4*)(vb + ((size_t)(r0a + cx0) << 6));
            uint4 v01 = *(const uint4*)(vb + ((size_t)(r0a + cx1) << 6));
            uint4 v10 = *(const uint4*)(vb + ((size_t)(r1a + cx0) << 6));
            uint4 v11 = *(const uint4*)(vb + ((size_t)(r1a + cx1) << 6));

            accp(acc2, v00, w00);
            accp(acc2, v01, w01);
            accp(acc2, v10, w10);
            accp(acc2, v11, w11);
        }
    }

    const float inv = 1.f / esum;
    uint4 o;
    o.x = pk2(acc2[0].x * inv, acc2[0].y * inv);
    o.y = pk2(acc2[1].x * inv, acc2[1].y * inv);
    o.z = pk2(acc2[2].x * inv, acc2[2].y * inv);
    o.w = pk2(acc2[3].x * inv, acc2[3].y * inv);
    ((uint4*)(mid + (size_t)bq * 256 + h * 32))[cg] = o;
}

// ======================= launch =======================
extern "C" void kernel_launch(void* const* d_in, const int* in_sizes, int n_in,
                              void* d_out, int out_size, void* d_ws, size_t ws_size,
                              hipStream_t stream)
{
    const float* query  = (const float*)d_in[0];
    const float* refp   = (const float*)d_in[1];
    const float* inflat = (const float*)d_in[2];
    const float* W_val  = (const float*)d_in[5];
    const float* b_val  = (const float*)d_in[6];
    const float* W_off  = (const float*)d_in[7];
    const float* W_attn = (const float*)d_in[9];
    const float* b_off  = (const float*)d_in[8];
    const float* b_attn = (const float*)d_in[10];
    const float* W_out  = (const float*)d_in[11];
    const float* b_out  = (const float*)d_in[12];
    float* out = (float*)d_out;

    char* ws = (char*)d_ws;
    ushort_t* mid_bf   = (ushort_t*)ws;                               // 11,141,120
    ushort_t* value_bf = (ushort_t*)(ws + 11141120);                  // 11,141,120 head-major
    ushort_t* wvT      = (ushort_t*)(ws + 22282240);                  // 131,072
    ushort_t* woutT    = (ushort_t*)(ws + 22413312);                  // 131,072
    ushort_t* woaT     = (ushort_t*)(ws + 22544384);                  // 196,608
    float*    bias_oa  = (float*)   (ws + 22740992);                  // 1,536
    float*    offattn  = (float*)   (ws + 22742528);                  // 33,423,360

    dim3 blk(256);
    pack_weights<<<dim3(97), blk, 0, stream>>>(
        W_val, W_out, W_off, W_attn, b_off, b_attn,
        wvT, woutT, woaT, bias_oa);
    gemm_dual<<<dim3(510), blk, 0, stream>>>(
        inflat, wvT, b_val, value_bf, query, woaT, bias_oa, offattn);
    msda_sample_v3<<<dim3(2720), blk, 0, stream>>>(
        value_bf, refp, offattn, mid_bf);
    gemm_out<<<dim3(340), blk, 0, stream>>>(
        mid_bf, woutT, b_out, out);
}

// Round 5
// 176.714 us; speedup vs baseline: 1.0464x; 1.0464x over previous
//
#include <hip/hip_runtime.h>
#include <hip/hip_bf16.h>
#include <math.h>

typedef unsigned short ushort_t;
typedef __attribute__((ext_vector_type(8))) short bf16x8;
typedef __attribute__((ext_vector_type(4))) float f32x4;
typedef __attribute__((ext_vector_type(2))) float f32x2;

constexpr int BATCH   = 4;
constexpr int D_MODEL = 256;
constexpr int LEN_IN  = 5440;
constexpr int LEN_Q   = 5440;
constexpr int M_TOT   = BATCH * LEN_Q;   // 21760

#define ASG __attribute__((address_space(1)))
#define ASL __attribute__((address_space(3)))

__device__ __forceinline__ void gld16(const void* g, void* l) {
    __builtin_amdgcn_global_load_lds((ASG const void*)g, (ASL void*)l, 16, 0, 0);
}

__device__ __forceinline__ ushort_t bfbits(float x) {
    __hip_bfloat16 h = __float2bfloat16(x);
    ushort_t u; __builtin_memcpy(&u, &h, 2); return u;
}
__device__ __forceinline__ unsigned pk2(float a, float b) {
    return (unsigned)bfbits(a) | ((unsigned)bfbits(b) << 16);
}

// ======================= weight prep (tiny) =======================
__global__ __launch_bounds__(256) void pack_weights(
    const float* __restrict__ Wv, const float* __restrict__ Wout,
    const float* __restrict__ Wo, const float* __restrict__ Wa,
    const float* __restrict__ b_off, const float* __restrict__ b_attn,
    ushort_t* __restrict__ wvT, ushort_t* __restrict__ woutT,
    ushort_t* __restrict__ woaT, float* __restrict__ bias_oa)
{
    const int blk = blockIdx.x, t = threadIdx.x;
    if (blk < 64) {
        const float* src = (blk < 32) ? Wv : Wout;
        ushort_t*    dst = (blk < 32) ? wvT : woutT;
        const int k0 = (blk & 31) * 8;
        float f[8];
#pragma unroll
        for (int i = 0; i < 8; i++) f[i] = src[(k0 + i) * 256 + t];
        *(uint4*)(dst + t * 256 + k0) =
            make_uint4(pk2(f[0], f[1]), pk2(f[2], f[3]),
                       pk2(f[4], f[5]), pk2(f[6], f[7]));
    } else if (blk < 96) {
        const int k0 = (blk - 64) * 8;
#pragma unroll
        for (int rep = 0; rep < 2; rep++) {
            const int j = (rep == 0) ? t : 256 + t;
            if (rep == 1 && t >= 128) break;
            float f[8];
#pragma unroll
            for (int i = 0; i < 8; i++)
                f[i] = (j < 256) ? Wo[(k0 + i) * 256 + j]
                                 : Wa[(k0 + i) * 128 + (j - 256)];
            *(uint4*)(woaT + j * 256 + k0) =
                make_uint4(pk2(f[0], f[1]), pk2(f[2], f[3]),
                           pk2(f[4], f[5]), pk2(f[6], f[7]));
        }
    } else {
        bias_oa[t] = b_off[t];
        if (t < 128) bias_oa[256 + t] = b_attn[t];
    }
}

// ======================= bf16 MFMA GEMM core (N-blocked) =======================
// OUT_MODE: 0 = f32 row-major, 2 = bf16 head-major value
template <int OUT_MODE, bool A_F32, int NB>
__device__ __forceinline__ void gemm_core(
    const void* __restrict__ Ap, const ushort_t* __restrict__ BT,
    const float* __restrict__ bias, void* __restrict__ Cp, int N,
    int bm, int bn, ushort_t* As, ushort_t* Bs)
{
    const int tid  = threadIdx.x;
    const int wave = tid >> 6, lane = tid & 63;
    const int wm = (wave >> 1) * 64, wn = (wave & 1) * 64;
    const int c0 = 2 * wave, c1 = 2 * wave + 1;
    const int kb = (lane & 3) * 8;
    const int ar0 = bm + c0 * 16 + (lane >> 2);
    const int ar1 = bm + c1 * 16 + (lane >> 2);
    const ushort_t* gA0h = nullptr; const ushort_t* gA1h = nullptr;
    const float*    gA0f = nullptr; const float*    gA1f = nullptr;
    if (A_F32) {
        gA0f = (const float*)Ap + (size_t)ar0 * 256 + kb;
        gA1f = (const float*)Ap + (size_t)ar1 * 256 + kb;
    } else {
        gA0h = (const ushort_t*)Ap + (size_t)ar0 * 256 + kb;
        gA1h = (const ushort_t*)Ap + (size_t)ar1 * 256 + kb;
    }
    const ushort_t* gB0[NB]; const ushort_t* gB1[NB];
    ushort_t* lB0[NB]; ushort_t* lB1[NB];
#pragma unroll
    for (int nb = 0; nb < NB; nb++) {
        gB0[nb] = BT + (size_t)(bn + nb * 128 + c0 * 16 + (lane >> 2)) * 256 + kb;
        gB1[nb] = BT + (size_t)(bn + nb * 128 + c1 * 16 + (lane >> 2)) * 256 + kb;
        lB0[nb] = Bs + nb * 4096 + c0 * 512;
        lB1[nb] = Bs + nb * 4096 + c1 * 512;
    }
    ushort_t* lA0 = As + c0 * 512;   // wave-uniform chunk base
    ushort_t* lA1 = As + c1 * 512;

    f32x4 acc[NB][4][4] = {};
    const int row = lane & 15, kg = (lane >> 4) * 8;
    for (int kt = 0; kt < 8; kt++) {
        if (A_F32) {
            float4 a0 = *(const float4*)gA0f;
            float4 a1 = *(const float4*)(gA0f + 4);
            float4 b0 = *(const float4*)gA1f;
            float4 b1 = *(const float4*)(gA1f + 4);
            *(uint4*)(lA0 + lane * 8) =
                make_uint4(pk2(a0.x, a0.y), pk2(a0.z, a0.w),
                           pk2(a1.x, a1.y), pk2(a1.z, a1.w));
            *(uint4*)(lA1 + lane * 8) =
                make_uint4(pk2(b0.x, b0.y), pk2(b0.z, b0.w),
                           pk2(b1.x, b1.y), pk2(b1.z, b1.w));
            gA0f += 32; gA1f += 32;
        } else {
            gld16(gA0h, lA0); gld16(gA1h, lA1);
            gA0h += 32; gA1h += 32;
        }
#pragma unroll
        for (int nb = 0; nb < NB; nb++) {
            gld16(gB0[nb], lB0[nb]); gld16(gB1[nb], lB1[nb]);
            gB0[nb] += 32; gB1[nb] += 32;
        }
        __syncthreads();
        bf16x8 af[4];
#pragma unroll
        for (int i = 0; i < 4; i++)
            af[i] = *(const bf16x8*)(As + (wm + i * 16 + row) * 32 + kg);
#pragma unroll
        for (int nb = 0; nb < NB; nb++) {
            bf16x8 bfr[4];
#pragma unroll
            for (int j = 0; j < 4; j++)
                bfr[j] = *(const bf16x8*)(Bs + nb * 4096 + (wn + j * 16 + row) * 32 + kg);
#pragma unroll
            for (int i = 0; i < 4; i++)
#pragma unroll
                for (int j = 0; j < 4; j++)
                    acc[nb][i][j] = __builtin_amdgcn_mfma_f32_16x16x32_bf16(
                        af[i], bfr[j], acc[nb][i][j], 0, 0, 0);
        }
        __syncthreads();
    }

    const int col = lane & 15, rbase = (lane >> 4) * 4;
#pragma unroll
    for (int nb = 0; nb < NB; nb++) {
#pragma unroll
        for (int j = 0; j < 4; j++) {
            const int cc = bn + nb * 128 + wn + j * 16 + col;
            const float bv = bias[cc];
#pragma unroll
            for (int i = 0; i < 4; i++) {
                const int rr = bm + wm + i * 16 + rbase;
#pragma unroll
                for (int r = 0; r < 4; r++) {
                    const float v = acc[nb][i][j][r] + bv;
                    const int m = rr + r;
                    if (OUT_MODE == 0) {
                        ((float*)Cp)[(size_t)m * N + cc] = v;
                    } else {
                        // value head-major: [b][head][pix][32]
                        const int bb  = m / LEN_IN;
                        const int pix = m - bb * LEN_IN;
                        const int head = cc >> 5, ch = cc & 31;
                        ((ushort_t*)Cp)[((size_t)((bb * 8 + head) * LEN_IN + pix) << 5) + ch] = bfbits(v);
                    }
                }
            }
        }
    }
}

// 510 blocks: [0,170) value NB=2; [170,340) offattn bn{0,128}; [340,510) offattn bn{256}
__global__ __launch_bounds__(256) void gemm_dual(
    const float* __restrict__ inflat, const ushort_t* __restrict__ wvT,
    const float* __restrict__ b_val, ushort_t* __restrict__ value_bf,
    const float* __restrict__ query, const ushort_t* __restrict__ woaT,
    const float* __restrict__ bias_oa, float* __restrict__ offattn)
{
    __shared__ ushort_t As[128 * 32];
    __shared__ ushort_t Bs[2 * 128 * 32];
    const int blk = blockIdx.x;
    if (blk < 170) {
        gemm_core<2, true, 2>(inflat, wvT, b_val, value_bf, 256,
                              blk * 128, 0, As, Bs);
    } else if (blk < 340) {
        gemm_core<0, true, 2>(query, woaT, bias_oa, offattn, 384,
                              (blk - 170) * 128, 0, As, Bs);
    } else {
        gemm_core<0, true, 1>(query, woaT, bias_oa, offattn, 384,
                              (blk - 340) * 128, 256, As, Bs);
    }
}

__global__ __launch_bounds__(256) void gemm_out(
    const ushort_t* __restrict__ mid_bf, const ushort_t* __restrict__ woutT,
    const float* __restrict__ b_out, float* __restrict__ out)
{
    __shared__ ushort_t As[128 * 32];
    __shared__ ushort_t Bs[128 * 32];
    const int bn = (blockIdx.x & 1) * 128, bm = (blockIdx.x >> 1) * 128;
    gemm_core<0, false, 1>(mid_bf, woutT, b_out, out, 256, bm, bn, As, Bs);
}

// ======================= softmax + bilinear sampling v4 =======================
// Phase-split: phase 1 computes each (q,p)'s weights/addresses ONCE (256
// threads = 64 q x 16 p; softmax max/sum via shfl_xor in the 16-lane point
// group), stored to XOR-swizzled LDS ([q][p^q] -> 2-way conflicts = free).
// Phase 2 gathers: 4 channel-split lanes per query read params via
// ds_read_b128 instead of recomputing coord math 4x.
__device__ __forceinline__ void accd(f32x2& a, unsigned u, f32x2 w) {
    f32x2 v;
    v.x = __uint_as_float(u << 16);
    v.y = __uint_as_float(u & 0xFFFF0000u);
    a = w * v + a;   // ffp-contract -> v_pk_fma_f32
}
__device__ __forceinline__ void accp(f32x2* a, uint4 u, float wf) {
    const f32x2 w = {wf, wf};
    accd(a[0], u.x, w); accd(a[1], u.y, w);
    accd(a[2], u.z, w); accd(a[3], u.w, w);
}

__global__ __launch_bounds__(256) void msda_sample_v4(
    const ushort_t* __restrict__ value,   // [B*8][5440][32] bf16
    const float* __restrict__ refp,
    const float* __restrict__ offattn,
    ushort_t* __restrict__ mid)
{
    __shared__ float4 wLDS[64][16];       // 16 KB  (w00,w01,w10,w11)
    __shared__ float4 aLDS[64][16];       // 16 KB  (off00, dxB, dyB, -)
    __shared__ float  esLDS[64];

    const int tid = threadIdx.x;
    const unsigned bid = blockIdx.x;
    // XCD-pinned slice mapping: 85 q-chunks per (b,h), 4 (b,h) per XCD
    const int xcd   = bid & 7;
    const int pos   = bid >> 3;           // 0..339
    const int slice = pos / 85;           // 0..3
    const int qc    = pos - slice * 85;   // 0..84
    const int bh    = xcd * 4 + slice;    // 0..31
    const int b     = bh >> 3, h = bh & 7;
    const int bqbase = b * LEN_Q + qc * 64;

    // ---------------- phase 1: per-(q,p) params, computed once ----------------
    {
        const int p  = tid & 15;
        const int qg = tid >> 4;          // 0..15
        const int l  = p >> 2;
        const int shift = 6 - l;
        const int W  = 1 << shift;
        const float fW   = (float)W;
        const float invW = __uint_as_float((unsigned)(127 - shift) << 23); // exact 2^-shift
        const int st = (l == 0) ? 0 : (l == 1) ? 4096 : (l == 2) ? 5120 : 5376;

#pragma unroll
        for (int it = 0; it < 4; it++) {
            const int ql = it * 16 + qg;  // 0..63
            const int bq = bqbase + ql;
            const float* oab = offattn + (size_t)bq * 384;
            const float2 off = *(const float2*)(oab + h * 32 + p * 2);
            const float  lgv = oab[256 + h * 16 + p];
            const float2 rl  = *(const float2*)(refp + (size_t)bq * 8 + l * 2);

            float mx = lgv;
            mx = fmaxf(mx, __shfl_xor(mx, 1));
            mx = fmaxf(mx, __shfl_xor(mx, 2));
            mx = fmaxf(mx, __shfl_xor(mx, 4));
            mx = fmaxf(mx, __shfl_xor(mx, 8));
            const float e = __expf(lgv - mx);
            float es = e;
            es += __shfl_xor(es, 1);
            es += __shfl_xor(es, 2);
            es += __shfl_xor(es, 4);
            es += __shfl_xor(es, 8);

            const float x = (rl.x + off.x * invW) * fW - 0.5f;
            const float y = (rl.y + off.y * invW) * fW - 0.5f;
            const float x0f = floorf(x), y0f = floorf(y);
            const float wx = x - x0f, wy = y - y0f;
            const int ix0 = (int)x0f, iy0 = (int)y0f;
            const int ix1 = ix0 + 1,  iy1 = iy0 + 1;
            const float vx0 = (ix0 >= 0 && ix0 < W) ? 1.f : 0.f;
            const float vx1 = (ix1 >= 0 && ix1 < W) ? 1.f : 0.f;
            const float vy0 = (iy0 >= 0 && iy0 < W) ? 1.f : 0.f;
            const float vy1 = (iy1 >= 0 && iy1 < W) ? 1.f : 0.f;
            const int cx0 = min(max(ix0, 0), W - 1);
            const int cx1 = min(max(ix1, 0), W - 1);
            const int cy0 = min(max(iy0, 0), W - 1);
            const int cy1 = min(max(iy1, 0), W - 1);
            const float hx0 = (1.f - wx) * vx0, hx1 = wx * vx1;
            const float hy0 = (1.f - wy) * vy0, hy1 = wy * vy1;

            const int off00 = (st + (cy0 << shift) + cx0) << 6;
            const int dxB   = (cx1 - cx0) << 6;
            const int dyB   = ((cy1 - cy0) << shift) << 6;

            const int ps = p ^ (ql & 15); // XOR swizzle -> 2-way banks both phases
            wLDS[ql][ps] = make_float4(e * hx0 * hy0, e * hx1 * hy0,
                                       e * hx0 * hy1, e * hx1 * hy1);
            aLDS[ql][ps] = make_float4(__int_as_float(off00), __int_as_float(dxB),
                                       __int_as_float(dyB), 0.f);
            if (p == 0) esLDS[ql] = es;
        }
    }
    __syncthreads();

    // ---------------- phase 2: gather + blend ----------------
    const int ql = tid >> 2;              // 0..63
    const int cg = tid & 3;               // channel group (8 ch = 16 B)
    const int bq = bqbase + ql;
    const char* vb = (const char*)value + (size_t)bh * (LEN_IN * 64) + cg * 16;
    const float inv = 1.f / esLDS[ql];
    const int qs = ql & 15;

    f32x2 acc2[4];
#pragma unroll
    for (int d = 0; d < 4; d++) acc2[d] = (f32x2){0.f, 0.f};

#pragma unroll
    for (int pp = 0; pp < 16; pp++) {
        const float4 w  = wLDS[ql][pp ^ qs];
        const float4 ai = aLDS[ql][pp ^ qs];
        const int o00 = __float_as_int(ai.x);
        const int dx  = __float_as_int(ai.y);
        const int dy  = __float_as_int(ai.z);
        const char* c00 = vb + o00;
        uint4 v00 = *(const uint4*)(c00);
        uint4 v01 = *(const uint4*)(c00 + dx);
        uint4 v10 = *(const uint4*)(c00 + dy);
        uint4 v11 = *(const uint4*)(c00 + dx + dy);
        accp(acc2, v00, w.x);
        accp(acc2, v01, w.y);
        accp(acc2, v10, w.z);
        accp(acc2, v11, w.w);
    }

    uint4 o;
    o.x = pk2(acc2[0].x * inv, acc2[0].y * inv);
    o.y = pk2(acc2[1].x * inv, acc2[1].y * inv);
    o.z = pk2(acc2[2].x * inv, acc2[2].y * inv);
    o.w = pk2(acc2[3].x * inv, acc2[3].y * inv);
    ((uint4*)(mid + (size_t)bq * 256 + h * 32))[cg] = o;
}

// ======================= launch =======================
extern "C" void kernel_launch(void* const* d_in, const int* in_sizes, int n_in,
                              void* d_out, int out_size, void* d_ws, size_t ws_size,
                              hipStream_t stream)
{
    const float* query  = (const float*)d_in[0];
    const float* refp   = (const float*)d_in[1];
    const float* inflat = (const float*)d_in[2];
    const float* W_val  = (const float*)d_in[5];
    const float* b_val  = (const float*)d_in[6];
    const float* W_off  = (const float*)d_in[7];
    const float* W_attn = (const float*)d_in[9];
    const float* b_off  = (const float*)d_in[8];
    const float* b_attn = (const float*)d_in[10];
    const float* W_out  = (const float*)d_in[11];
    const float* b_out  = (const float*)d_in[12];
    float* out = (float*)d_out;

    char* ws = (char*)d_ws;
    ushort_t* mid_bf   = (ushort_t*)ws;                               // 11,141,120
    ushort_t* value_bf = (ushort_t*)(ws + 11141120);                  // 11,141,120 head-major
    ushort_t* wvT      = (ushort_t*)(ws + 22282240);                  // 131,072
    ushort_t* woutT    = (ushort_t*)(ws + 22413312);                  // 131,072
    ushort_t* woaT     = (ushort_t*)(ws + 22544384);                  // 196,608
    float*    bias_oa  = (float*)   (ws + 22740992);                  // 1,536
    float*    offattn  = (float*)   (ws + 22742528);                  // 33,423,360

    dim3 blk(256);
    pack_weights<<<dim3(97), blk, 0, stream>>>(
        W_val, W_out, W_off, W_attn, b_off, b_attn,
        wvT, woutT, woaT, bias_oa);
    gemm_dual<<<dim3(510), blk, 0, stream>>>(
        inflat, wvT, b_val, value_bf, query, woaT, bias_oa, offattn);
    msda_sample_v4<<<dim3(2720), blk, 0, stream>>>(
        value_bf, refp, offattn, mid_bf);
    gemm_out<<<dim3(340), blk, 0, stream>>>(
        mid_bf, woutT, b_out, out);
}

// Round 6
// 175.956 us; speedup vs baseline: 1.0509x; 1.0043x over previous
//
#include <hip/hip_runtime.h>
#include <hip/hip_bf16.h>
#include <math.h>

typedef unsigned short ushort_t;
typedef __attribute__((ext_vector_type(8))) short bf16x8;
typedef __attribute__((ext_vector_type(4))) float f32x4;
typedef __attribute__((ext_vector_type(2))) float f32x2;

constexpr int BATCH   = 4;
constexpr int D_MODEL = 256;
constexpr int LEN_IN  = 5440;
constexpr int LEN_Q   = 5440;
constexpr int M_TOT   = BATCH * LEN_Q;   // 21760

#define ASG __attribute__((address_space(1)))
#define ASL __attribute__((address_space(3)))

__device__ __forceinline__ void gld16(const void* g, void* l) {
    __builtin_amdgcn_global_load_lds((ASG const void*)g, (ASL void*)l, 16, 0, 0);
}

__device__ __forceinline__ ushort_t bfbits(float x) {
    __hip_bfloat16 h = __float2bfloat16(x);
    ushort_t u; __builtin_memcpy(&u, &h, 2); return u;
}
__device__ __forceinline__ unsigned pk2(float a, float b) {
    return (unsigned)bfbits(a) | ((unsigned)bfbits(b) << 16);
}

// ======================= weight prep (tiny) =======================
__global__ __launch_bounds__(256) void pack_weights(
    const float* __restrict__ Wv, const float* __restrict__ Wout,
    const float* __restrict__ Wo, const float* __restrict__ Wa,
    const float* __restrict__ b_off, const float* __restrict__ b_attn,
    ushort_t* __restrict__ wvT, ushort_t* __restrict__ woutT,
    ushort_t* __restrict__ woaT, float* __restrict__ bias_oa)
{
    const int blk = blockIdx.x, t = threadIdx.x;
    if (blk < 64) {
        const float* src = (blk < 32) ? Wv : Wout;
        ushort_t*    dst = (blk < 32) ? wvT : woutT;
        const int k0 = (blk & 31) * 8;
        float f[8];
#pragma unroll
        for (int i = 0; i < 8; i++) f[i] = src[(k0 + i) * 256 + t];
        *(uint4*)(dst + t * 256 + k0) =
            make_uint4(pk2(f[0], f[1]), pk2(f[2], f[3]),
                       pk2(f[4], f[5]), pk2(f[6], f[7]));
    } else if (blk < 96) {
        const int k0 = (blk - 64) * 8;
#pragma unroll
        for (int rep = 0; rep < 2; rep++) {
            const int j = (rep == 0) ? t : 256 + t;
            if (rep == 1 && t >= 128) break;
            float f[8];
#pragma unroll
            for (int i = 0; i < 8; i++)
                f[i] = (j < 256) ? Wo[(k0 + i) * 256 + j]
                                 : Wa[(k0 + i) * 128 + (j - 256)];
            *(uint4*)(woaT + j * 256 + k0) =
                make_uint4(pk2(f[0], f[1]), pk2(f[2], f[3]),
                           pk2(f[4], f[5]), pk2(f[6], f[7]));
        }
    } else {
        bias_oa[t] = b_off[t];
        if (t < 128) bias_oa[256 + t] = b_attn[t];
    }
}

// ======================= bf16 MFMA GEMM core (N-blocked, double-buffered) =====
// OUT_MODE: 0 = f32 row-major, 2 = bf16 head-major value
// A_F32: A is raw f32; reg-stage (float4 x2 -> cvt -> ds_write_b128).
// Double-buffered LDS: stage kt+1 into buf^1 BEFORE computing kt ->
// ONE barrier per K-iter (9 total vs 16); the barrier's vmcnt drain lands
// after the MFMA cluster instead of immediately after issue.
template <int OUT_MODE, bool A_F32, int NB>
__device__ __forceinline__ void gemm_core(
    const void* __restrict__ Ap, const ushort_t* __restrict__ BT,
    const float* __restrict__ bias, void* __restrict__ Cp, int N,
    int bm, int bn, ushort_t* As, ushort_t* Bs)
{
    const int tid  = threadIdx.x;
    const int wave = tid >> 6, lane = tid & 63;
    const int wm = (wave >> 1) * 64, wn = (wave & 1) * 64;
    const int c0 = 2 * wave, c1 = 2 * wave + 1;
    const int kb = (lane & 3) * 8;
    const int ar0 = bm + c0 * 16 + (lane >> 2);
    const int ar1 = bm + c1 * 16 + (lane >> 2);
    const ushort_t* gA0h = nullptr; const ushort_t* gA1h = nullptr;
    const float*    gA0f = nullptr; const float*    gA1f = nullptr;
    if (A_F32) {
        gA0f = (const float*)Ap + (size_t)ar0 * 256 + kb;
        gA1f = (const float*)Ap + (size_t)ar1 * 256 + kb;
    } else {
        gA0h = (const ushort_t*)Ap + (size_t)ar0 * 256 + kb;
        gA1h = (const ushort_t*)Ap + (size_t)ar1 * 256 + kb;
    }
    const ushort_t* gB0[NB]; const ushort_t* gB1[NB];
#pragma unroll
    for (int nb = 0; nb < NB; nb++) {
        gB0[nb] = BT + (size_t)(bn + nb * 128 + c0 * 16 + (lane >> 2)) * 256 + kb;
        gB1[nb] = BT + (size_t)(bn + nb * 128 + c1 * 16 + (lane >> 2)) * 256 + kb;
    }

    auto STAGE = [&](int kt, int buf) {
        ushort_t* as = As + buf * 4096;
        ushort_t* bs = Bs + buf * (NB * 4096);
        if (A_F32) {
            const float* a0 = gA0f + kt * 32;
            const float* a1 = gA1f + kt * 32;
            float4 x0 = *(const float4*)a0;
            float4 x1 = *(const float4*)(a0 + 4);
            float4 y0 = *(const float4*)a1;
            float4 y1 = *(const float4*)(a1 + 4);
            *(uint4*)(as + c0 * 512 + lane * 8) =
                make_uint4(pk2(x0.x, x0.y), pk2(x0.z, x0.w),
                           pk2(x1.x, x1.y), pk2(x1.z, x1.w));
            *(uint4*)(as + c1 * 512 + lane * 8) =
                make_uint4(pk2(y0.x, y0.y), pk2(y0.z, y0.w),
                           pk2(y1.x, y1.y), pk2(y1.z, y1.w));
        } else {
            gld16(gA0h + kt * 32, as + c0 * 512);
            gld16(gA1h + kt * 32, as + c1 * 512);
        }
#pragma unroll
        for (int nb = 0; nb < NB; nb++) {
            gld16(gB0[nb] + kt * 32, bs + nb * 4096 + c0 * 512);
            gld16(gB1[nb] + kt * 32, bs + nb * 4096 + c1 * 512);
        }
    };

    f32x4 acc[NB][4][4] = {};
    const int row = lane & 15, kg = (lane >> 4) * 8;

    STAGE(0, 0);
    __syncthreads();

    for (int kt = 0; kt < 8; kt++) {
        const int cur = kt & 1;
        if (kt < 7) STAGE(kt + 1, cur ^ 1);
        const ushort_t* as = As + cur * 4096;
        const ushort_t* bs = Bs + cur * (NB * 4096);
        bf16x8 af[4];
#pragma unroll
        for (int i = 0; i < 4; i++)
            af[i] = *(const bf16x8*)(as + (wm + i * 16 + row) * 32 + kg);
#pragma unroll
        for (int nb = 0; nb < NB; nb++) {
            bf16x8 bfr[4];
#pragma unroll
            for (int j = 0; j < 4; j++)
                bfr[j] = *(const bf16x8*)(bs + nb * 4096 + (wn + j * 16 + row) * 32 + kg);
#pragma unroll
            for (int i = 0; i < 4; i++)
#pragma unroll
                for (int j = 0; j < 4; j++)
                    acc[nb][i][j] = __builtin_amdgcn_mfma_f32_16x16x32_bf16(
                        af[i], bfr[j], acc[nb][i][j], 0, 0, 0);
        }
        __syncthreads();   // drains staged loads for buf^1; WAR-safe for next STAGE
    }

    const int col = lane & 15, rbase = (lane >> 4) * 4;
#pragma unroll
    for (int nb = 0; nb < NB; nb++) {
#pragma unroll
        for (int j = 0; j < 4; j++) {
            const int cc = bn + nb * 128 + wn + j * 16 + col;
            const float bv = bias[cc];
#pragma unroll
            for (int i = 0; i < 4; i++) {
                const int rr = bm + wm + i * 16 + rbase;
#pragma unroll
                for (int r = 0; r < 4; r++) {
                    const float v = acc[nb][i][j][r] + bv;
                    const int m = rr + r;
                    if (OUT_MODE == 0) {
                        ((float*)Cp)[(size_t)m * N + cc] = v;
                    } else {
                        // value head-major: [b][head][pix][32]
                        const int bb  = m / LEN_IN;
                        const int pix = m - bb * LEN_IN;
                        const int head = cc >> 5, ch = cc & 31;
                        ((ushort_t*)Cp)[((size_t)((bb * 8 + head) * LEN_IN + pix) << 5) + ch] = bfbits(v);
                    }
                }
            }
        }
    }
}

// 510 blocks: [0,170) value NB=2; [170,340) offattn bn{0,128}; [340,510) offattn bn{256}
__global__ __launch_bounds__(256) void gemm_dual(
    const float* __restrict__ inflat, const ushort_t* __restrict__ wvT,
    const float* __restrict__ b_val, ushort_t* __restrict__ value_bf,
    const float* __restrict__ query, const ushort_t* __restrict__ woaT,
    const float* __restrict__ bias_oa, float* __restrict__ offattn)
{
    __shared__ ushort_t As[2 * 128 * 32];
    __shared__ ushort_t Bs[2 * 2 * 128 * 32];
    const int blk = blockIdx.x;
    if (blk < 170) {
        gemm_core<2, true, 2>(inflat, wvT, b_val, value_bf, 256,
                              blk * 128, 0, As, Bs);
    } else if (blk < 340) {
        gemm_core<0, true, 2>(query, woaT, bias_oa, offattn, 384,
                              (blk - 170) * 128, 0, As, Bs);
    } else {
        gemm_core<0, true, 1>(query, woaT, bias_oa, offattn, 384,
                              (blk - 340) * 128, 256, As, Bs);
    }
}

__global__ __launch_bounds__(256) void gemm_out(
    const ushort_t* __restrict__ mid_bf, const ushort_t* __restrict__ woutT,
    const float* __restrict__ b_out, float* __restrict__ out)
{
    __shared__ ushort_t As[2 * 128 * 32];
    __shared__ ushort_t Bs[2 * 128 * 32];
    const int bn = (blockIdx.x & 1) * 128, bm = (blockIdx.x >> 1) * 128;
    gemm_core<0, false, 1>(mid_bf, woutT, b_out, out, 256, bm, bn, As, Bs);
}

// ======================= softmax + bilinear sampling v4b =======================
// Phase-split msda. aLDS compressed to int2 (off00; dx<<16|dy) -> 24.3 KB LDS
// -> 6 blocks/CU (was 4) -> ~24 waves/CU for the latency-bound gather.
__device__ __forceinline__ void accd(f32x2& a, unsigned u, f32x2 w) {
    f32x2 v;
    v.x = __uint_as_float(u << 16);
    v.y = __uint_as_float(u & 0xFFFF0000u);
    a = w * v + a;   // ffp-contract -> v_pk_fma_f32
}
__device__ __forceinline__ void accp(f32x2* a, uint4 u, float wf) {
    const f32x2 w = {wf, wf};
    accd(a[0], u.x, w); accd(a[1], u.y, w);
    accd(a[2], u.z, w); accd(a[3], u.w, w);
}

__global__ __launch_bounds__(256) void msda_sample_v4(
    const ushort_t* __restrict__ value,   // [B*8][5440][32] bf16
    const float* __restrict__ refp,
    const float* __restrict__ offattn,
    ushort_t* __restrict__ mid)
{
    __shared__ float4 wLDS[64][16];       // 16 KB  (w00,w01,w10,w11)
    __shared__ int2   aLDS[64][16];       // 8 KB   (off00, dx<<16|dy)
    __shared__ float  esLDS[64];

    const int tid = threadIdx.x;
    const unsigned bid = blockIdx.x;
    // XCD-pinned slice mapping: 85 q-chunks per (b,h), 4 (b,h) per XCD
    const int xcd   = bid & 7;
    const int pos   = bid >> 3;           // 0..339
    const int slice = pos / 85;           // 0..3
    const int qc    = pos - slice * 85;   // 0..84
    const int bh    = xcd * 4 + slice;    // 0..31
    const int b     = bh >> 3, h = bh & 7;
    const int bqbase = b * LEN_Q + qc * 64;

    // ---------------- phase 1: per-(q,p) params, computed once ----------------
    {
        const int p  = tid & 15;
        const int qg = tid >> 4;          // 0..15
        const int l  = p >> 2;
        const int shift = 6 - l;
        const int W  = 1 << shift;
        const float fW   = (float)W;
        const float invW = __uint_as_float((unsigned)(127 - shift) << 23); // exact 2^-shift
        const int st = (l == 0) ? 0 : (l == 1) ? 4096 : (l == 2) ? 5120 : 5376;

#pragma unroll
        for (int it = 0; it < 4; it++) {
            const int ql = it * 16 + qg;  // 0..63
            const int bq = bqbase + ql;
            const float* oab = offattn + (size_t)bq * 384;
            const float2 off = *(const float2*)(oab + h * 32 + p * 2);
            const float  lgv = oab[256 + h * 16 + p];
            const float2 rl  = *(const float2*)(refp + (size_t)bq * 8 + l * 2);

            float mx = lgv;
            mx = fmaxf(mx, __shfl_xor(mx, 1));
            mx = fmaxf(mx, __shfl_xor(mx, 2));
            mx = fmaxf(mx, __shfl_xor(mx, 4));
            mx = fmaxf(mx, __shfl_xor(mx, 8));
            const float e = __expf(lgv - mx);
            float es = e;
            es += __shfl_xor(es, 1);
            es += __shfl_xor(es, 2);
            es += __shfl_xor(es, 4);
            es += __shfl_xor(es, 8);

            const float x = (rl.x + off.x * invW) * fW - 0.5f;
            const float y = (rl.y + off.y * invW) * fW - 0.5f;
            const float x0f = floorf(x), y0f = floorf(y);
            const float wx = x - x0f, wy = y - y0f;
            const int ix0 = (int)x0f, iy0 = (int)y0f;
            const int ix1 = ix0 + 1,  iy1 = iy0 + 1;
            const float vx0 = (ix0 >= 0 && ix0 < W) ? 1.f : 0.f;
            const float vx1 = (ix1 >= 0 && ix1 < W) ? 1.f : 0.f;
            const float vy0 = (iy0 >= 0 && iy0 < W) ? 1.f : 0.f;
            const float vy1 = (iy1 >= 0 && iy1 < W) ? 1.f : 0.f;
            const int cx0 = min(max(ix0, 0), W - 1);
            const int cx1 = min(max(ix1, 0), W - 1);
            const int cy0 = min(max(iy0, 0), W - 1);
            const int cy1 = min(max(iy1, 0), W - 1);
            const float hx0 = (1.f - wx) * vx0, hx1 = wx * vx1;
            const float hy0 = (1.f - wy) * vy0, hy1 = wy * vy1;

            const int off00 = (st + (cy0 << shift) + cx0) << 6;
            const int dxB   = (cx1 - cx0) << 6;                 // 0 or 64
            const int dyB   = ((cy1 - cy0) << shift) << 6;      // 0 .. 4096

            const int ps = p ^ (ql & 15); // XOR swizzle -> 2-way banks both phases
            wLDS[ql][ps] = make_float4(e * hx0 * hy0, e * hx1 * hy0,
                                       e * hx0 * hy1, e * hx1 * hy1);
            aLDS[ql][ps] = make_int2(off00, (dxB << 16) | dyB);
            if (p == 0) esLDS[ql] = es;
        }
    }
    __syncthreads();

    // ---------------- phase 2: gather + blend ----------------
    const int ql = tid >> 2;              // 0..63
    const int cg = tid & 3;               // channel group (8 ch = 16 B)
    const int bq = bqbase + ql;
    const char* vb = (const char*)value + (size_t)bh * (LEN_IN * 64) + cg * 16;
    const float inv = 1.f / esLDS[ql];
    const int qs = ql & 15;

    f32x2 acc2[4];
#pragma unroll
    for (int d = 0; d < 4; d++) acc2[d] = (f32x2){0.f, 0.f};

#pragma unroll
    for (int pp = 0; pp < 16; pp++) {
        const float4 w  = wLDS[ql][pp ^ qs];
        const int2   ai = aLDS[ql][pp ^ qs];
        const int o00 = ai.x;
        const int dx  = ai.y >> 16;
        const int dy  = ai.y & 0xFFFF;
        const char* c00 = vb + o00;
        uint4 v00 = *(const uint4*)(c00);
        uint4 v01 = *(const uint4*)(c00 + dx);
        uint4 v10 = *(const uint4*)(c00 + dy);
        uint4 v11 = *(const uint4*)(c00 + dx + dy);
        accp(acc2, v00, w.x);
        accp(acc2, v01, w.y);
        accp(acc2, v10, w.z);
        accp(acc2, v11, w.w);
    }

    uint4 o;
    o.x = pk2(acc2[0].x * inv, acc2[0].y * inv);
    o.y = pk2(acc2[1].x * inv, acc2[1].y * inv);
    o.z = pk2(acc2[2].x * inv, acc2[2].y * inv);
    o.w = pk2(acc2[3].x * inv, acc2[3].y * inv);
    ((uint4*)(mid + (size_t)bq * 256 + h * 32))[cg] = o;
}

// ======================= launch =======================
extern "C" void kernel_launch(void* const* d_in, const int* in_sizes, int n_in,
                              void* d_out, int out_size, void* d_ws, size_t ws_size,
                              hipStream_t stream)
{
    const float* query  = (const float*)d_in[0];
    const float* refp   = (const float*)d_in[1];
    const float* inflat = (const float*)d_in[2];
    const float* W_val  = (const float*)d_in[5];
    const float* b_val  = (const float*)d_in[6];
    const float* W_off  = (const float*)d_in[7];
    const float* W_attn = (const float*)d_in[9];
    const float* b_off  = (const float*)d_in[8];
    const float* b_attn = (const float*)d_in[10];
    const float* W_out  = (const float*)d_in[11];
    const float* b_out  = (const float*)d_in[12];
    float* out = (float*)d_out;

    char* ws = (char*)d_ws;
    ushort_t* mid_bf   = (ushort_t*)ws;                               // 11,141,120
    ushort_t* value_bf = (ushort_t*)(ws + 11141120);                  // 11,141,120 head-major
    ushort_t* wvT      = (ushort_t*)(ws + 22282240);                  // 131,072
    ushort_t* woutT    = (ushort_t*)(ws + 22413312);                  // 131,072
    ushort_t* woaT     = (ushort_t*)(ws + 22544384);                  // 196,608
    float*    bias_oa  = (float*)   (ws + 22740992);                  // 1,536
    float*    offattn  = (float*)   (ws + 22742528);                  // 33,423,360

    dim3 blk(256);
    pack_weights<<<dim3(97), blk, 0, stream>>>(
        W_val, W_out, W_off, W_attn, b_off, b_attn,
        wvT, woutT, woaT, bias_oa);
    gemm_dual<<<dim3(510), blk, 0, stream>>>(
        inflat, wvT, b_val, value_bf, query, woaT, bias_oa, offattn);
    msda_sample_v4<<<dim3(2720), blk, 0, stream>>>(
        value_bf, refp, offattn, mid_bf);
    gemm_out<<<dim3(340), blk, 0, stream>>>(
        mid_bf, woutT, b_out, out);
}